// Round 6
// baseline (429.287 us; speedup 1.0000x reference)
//
#include <hip/hip_runtime.h>
#include <math.h>

#define B_ 4
#define C_ 512
#define L_ 4096
#define H_ 8
#define DH_ 64
#define MLP_ 2048
#define BL_ (B_*L_)      // 16384
#define LK_ (L_+1)       // 4097

typedef _Float16 f16;
typedef _Float16 f16x8 __attribute__((ext_vector_type(8)));
typedef _Float16 f16x4 __attribute__((ext_vector_type(4)));
typedef float f32x16 __attribute__((ext_vector_type(16)));

// async global->LDS, 16B per lane (m97 pattern)
__device__ __forceinline__ void gl16(void* lds, const void* g) {
  __builtin_amdgcn_global_load_lds((const __attribute__((address_space(1))) void*)g,
                                   (__attribute__((address_space(3))) void*)lds,
                                   16, 0, 0);
}

__device__ __forceinline__ float frcp(float x) { return __builtin_amdgcn_rcpf(x); }

// ---------------------------------------------------------------- transposes
__global__ __launch_bounds__(256) void transpose_w5(const float* __restrict__ Wq,
                                                    const float* __restrict__ Wk,
                                                    const float* __restrict__ Wv,
                                                    const float* __restrict__ Wkq,
                                                    const float* __restrict__ Wkk,
                                                    f16* __restrict__ dst) {
  int z = blockIdx.z;
  const float* W = (z == 0) ? Wq : (z == 1) ? Wk : (z == 2) ? Wv : (z == 3) ? Wkq : Wkk;
  f16* Wt = dst + (size_t)z * C_ * C_;
  __shared__ float tile[32][33];
  int n0 = blockIdx.x * 32, k0 = blockIdx.y * 32;
  int tx = threadIdx.x & 31, ty = threadIdx.x >> 5;
#pragma unroll
  for (int i = 0; i < 4; ++i)
    tile[ty + i * 8][tx] = W[(size_t)(k0 + ty + i * 8) * C_ + n0 + tx];
  __syncthreads();
#pragma unroll
  for (int i = 0; i < 4; ++i)
    Wt[(size_t)(n0 + ty + i * 8) * C_ + k0 + tx] = (f16)tile[tx][ty + i * 8];
}

__global__ __launch_bounds__(256) void transpose_w(const float* __restrict__ W,
                                                   f16* __restrict__ Wt, int K, int N) {
  __shared__ float tile[32][33];
  int n0 = blockIdx.x * 32, k0 = blockIdx.y * 32;
  int tx = threadIdx.x & 31, ty = threadIdx.x >> 5;
#pragma unroll
  for (int i = 0; i < 4; ++i)
    tile[ty + i * 8][tx] = W[(size_t)(k0 + ty + i * 8) * N + n0 + tx];
  __syncthreads();
#pragma unroll
  for (int i = 0; i < 4; ++i)
    Wt[(size_t)(n0 + ty + i * 8) * K + k0 + tx] = (f16)tile[tx][ty + i * 8];
}

__global__ __launch_bounds__(256) void transpose_x(const float* __restrict__ x,
                                                   f16* __restrict__ xf) {
  __shared__ float tile[32][33];
  int b = blockIdx.z;
  int l0 = blockIdx.x * 32, c0 = blockIdx.y * 32;
  int tx = threadIdx.x & 31, ty = threadIdx.x >> 5;
#pragma unroll
  for (int i = 0; i < 4; ++i)
    tile[ty + i * 8][tx] = x[((size_t)b * C_ + c0 + ty + i * 8) * L_ + l0 + tx];
  __syncthreads();
#pragma unroll
  for (int i = 0; i < 4; ++i)
    xf[((size_t)b * L_ + l0 + ty + i * 8) * C_ + c0 + tx] = (f16)tile[tx][ty + i * 8];
}

// ------------------------------------------------- pack small param vectors
__global__ __launch_bounds__(256) void pack_params(
    const float* bq, const float* bk, const float* bv,
    const float* gq, const float* gk, const float* gv,
    const float* betaq, const float* betak, const float* betav,
    const float* bkq, const float* bkk,
    float* bqkv, float* gqkv, float* betaqkv, float* bphi) {
  int i = blockIdx.x * 256 + threadIdx.x;  // 0..1535
  int w = i >> 9, c = i & 511;
  bqkv[i]    = (w == 0 ? bq : (w == 1 ? bk : bv))[c];
  gqkv[i]    = (w == 0 ? gq : (w == 1 ? gk : gv))[c];
  betaqkv[i] = (w == 0 ? betaq : (w == 1 ? betak : betav))[c];
  if (i < 1024) bphi[i] = (i < 512) ? bkq[i] : bkk[i - 512];
}

// ---------------------------------------------------------------- GEMM (MFMA)
// C[M,N](f16) = act(A[M,K] @ Bt[N,K]^T + bias)  -- 128x128 tiles, BK=64, dbuf,
// core = v_mfma_f32_32x32x16_f16 (2x2 supertiles of 32x32 per 64x64 wave tile).
// A/B frag layout: lane holds T[row=lane&31][k=(lane>>5)*8+j]  (j=0..7, b128).
// C/D layout (m74/m101-verified): col=lane&31, row=(reg&3)+8*(reg>>2)+4*(lane>>5).
// EPI: 1 tanh(v)+1   2 gelu (tanh approx)   3 v/(Bot+1e-6)   5 plain bias
//      6 plain bias + a-residual + transposed f32 out (+x)    [MLP-down fusion]
template <int EPI>
__global__ __launch_bounds__(256, 2) void gemm64(const f16* __restrict__ A,
                                                 const f16* __restrict__ Bt,
                                                 const float* __restrict__ bias,
                                                 f16* __restrict__ Ch,
                                                 int N, int K,
                                                 const float* __restrict__ Bot,
                                                 const f16* __restrict__ Ares,
                                                 const float* __restrict__ Xres,
                                                 float* __restrict__ Fout,
                                                 long long zA, long long zB,
                                                 long long zC, long long zBias,
                                                 long long zBot) {
  __shared__ f16 smem[2 * 128 * 128];  // 64 KB: [As|Bs] x 2 buffers; epi: [128][128]
  A  += (size_t)blockIdx.z * zA;
  Bt += (size_t)blockIdx.z * zB;
  if (EPI != 6) Ch += (size_t)blockIdx.z * zC;
  if (EPI == 3) Bot += (size_t)blockIdx.z * zBot;
  else          bias += (size_t)blockIdx.z * zBias;

  const int tid = threadIdx.x;
  const int lane = tid & 63, wv = tid >> 6;
  const int wm = wv >> 1, wn = wv & 1;
  const int bm = blockIdx.x * 128, bn = blockIdx.y * 128;
  const int r32 = lane & 31, kh = lane >> 5;

  // staging: LDS[r][slot] holds global k-chunk slot^(r&7) (8 f16 chunks)
  const int srow = tid >> 3;
  const int schunk = (tid & 7) ^ (srow & 7);
  const f16* pa = A + (size_t)(bm + srow) * K + schunk * 8;
  const f16* pb = Bt + (size_t)(bn + srow) * K + schunk * 8;
  f16* la = smem + tid * 8;
  f16* lb = smem + 8192 + tid * 8;

  f32x16 acc[2][2] = {};

#pragma unroll
  for (int p = 0; p < 4; ++p) gl16(la + p * 2048, pa + (size_t)p * 32 * K);
#pragma unroll
  for (int p = 0; p < 4; ++p) gl16(lb + p * 2048, pb + (size_t)p * 32 * K);

  int cur = 0;
  for (int k0 = 0; k0 < K; k0 += 64) {
    __syncthreads();                 // buf(cur) staged; buf(nxt) readers done
    const int nxt = cur ^ 1;
    if (k0 + 64 < K) {
#pragma unroll
      for (int p = 0; p < 4; ++p) gl16(la + nxt * 16384 + p * 2048, pa + (size_t)p * 32 * K + k0 + 64);
#pragma unroll
      for (int p = 0; p < 4; ++p) gl16(lb + nxt * 16384 + p * 2048, pb + (size_t)p * 32 * K + k0 + 64);
    }
    const f16* As = smem + cur * 16384;
    const f16* Bs = As + 8192;
#pragma unroll
    for (int s = 0; s < 4; ++s) {    // 4 k-steps of 16
      const int sw = ((2 * s + kh) ^ (r32 & 7)) * 8;
      f16x8 af[2], bf[2];
      af[0] = *(const f16x8*)&As[(wm * 64 + r32) * 64 + sw];
      af[1] = *(const f16x8*)&As[(wm * 64 + 32 + r32) * 64 + sw];
      bf[0] = *(const f16x8*)&Bs[(wn * 64 + r32) * 64 + sw];
      bf[1] = *(const f16x8*)&Bs[(wn * 64 + 32 + r32) * 64 + sw];
#pragma unroll
      for (int ti = 0; ti < 2; ++ti)
#pragma unroll
        for (int tj = 0; tj < 2; ++tj)
          acc[ti][tj] = __builtin_amdgcn_mfma_f32_32x32x16_f16(af[ti], bf[tj], acc[ti][tj], 0, 0, 0);
    }
    cur = nxt;
  }

  // ---- epilogue: act -> smem (col-chunk XOR swizzle) -> coalesced out
  __syncthreads();
#pragma unroll
  for (int tj = 0; tj < 2; ++tj) {
    int lc = wn * 64 + tj * 32 + r32;
    float bb = (EPI == 3) ? 0.f : bias[bn + lc];
#pragma unroll
    for (int ti = 0; ti < 2; ++ti) {
#pragma unroll
      for (int reg = 0; reg < 16; ++reg) {
        int lr = wm * 64 + ti * 32 + (reg & 3) + 8 * (reg >> 2) + 4 * kh;
        float v = acc[ti][tj][reg] + bb;
        if (EPI == 1) {
          v = 2.0f * frcp(1.0f + __expf(-2.0f * v));      // tanh(v)+1
        } else if (EPI == 2) {
          v = v * frcp(1.0f + __expf(-1.5957691f * (v + 0.044715f * v * v * v)));
        } else if (EPI == 3) {
          v = v * frcp(Bot[(size_t)(bm + lr) * H_ + ((bn + lc) >> 6)] + 1e-6f);
        }
        smem[lr * 128 + ((((lc >> 3) ^ (lr & 15)) << 3) | (lc & 7))] = (f16)v;
      }
    }
  }
  __syncthreads();

  if (EPI != 6) {
#pragma unroll
    for (int p = 0; p < 8; ++p) {
      int idx = p * 256 + tid;
      int row = idx >> 4, ch = idx & 15;
      f16x8 vv = *(const f16x8*)&smem[row * 128 + ((ch ^ (row & 15)) << 3)];
      *(f16x8*)&Ch[(size_t)(bm + row) * N + bn + ch * 8] = vv;
    }
  } else {
#pragma unroll
    for (int p = 0; p < 8; ++p) {
      int idx = p * 256 + tid;
      int row = idx >> 4, ch = idx & 15;
      f16x8 av = *(const f16x8*)&Ares[(size_t)(bm + row) * C_ + bn + ch * 8];
      f16* sp = &smem[row * 128 + ((ch ^ (row & 15)) << 3)];
      f16x8 sv = *(const f16x8*)sp;
#pragma unroll
      for (int jj = 0; jj < 8; ++jj) sv[jj] = (f16)((float)sv[jj] + (float)av[jj]);
      *(f16x8*)sp = sv;
    }
    __syncthreads();
    int c = tid & 127, lh = tid >> 7;
    int b = bm >> 12, lbase = (bm & 4095) + lh * 64;
    const float* xp = Xres + ((size_t)b * C_ + bn + c) * L_ + lbase;
    float* op = Fout + ((size_t)b * C_ + bn + c) * L_ + lbase;
    int chi = c >> 3, clo = c & 7;
#pragma unroll
    for (int s = 0; s < 16; ++s) {
      int l = lh * 64 + s * 4;
      float4 xv = *(const float4*)(xp + s * 4);
      float4 r;
      r.x = (float)smem[(l + 0) * 128 + (((chi ^ ((l + 0) & 15)) << 3) | clo)] + xv.x;
      r.y = (float)smem[(l + 1) * 128 + (((chi ^ ((l + 1) & 15)) << 3) | clo)] + xv.y;
      r.z = (float)smem[(l + 2) * 128 + (((chi ^ ((l + 2) & 15)) << 3) | clo)] + xv.z;
      r.w = (float)smem[(l + 3) * 128 + (((chi ^ ((l + 3) & 15)) << 3) | clo)] + xv.w;
      *(float4*)(op + s * 4) = r;
    }
  }
}

// ---------------------------------------------------------------- LayerNorm (f16 in/out)
// threeway=1: X is [49152][512] rows (token*3+which); out which*BL + token.
__global__ __launch_bounds__(256) void ln16(const f16* __restrict__ X,
                                            const float* __restrict__ g,
                                            const float* __restrict__ bta,
                                            f16* __restrict__ Y, int threeway) {
  int wv = threadIdx.x >> 6, lane = threadIdx.x & 63;
  int r = blockIdx.x * 4 + wv;
  int token = r, which = 0;
  if (threeway) { token = r / 3; which = r - token * 3; }
  const f16* xr = X + (size_t)r * C_;
  f16x8 v = *(const f16x8*)(xr + lane * 8);
  float vals[8];
  float s = 0.f, s2 = 0.f;
#pragma unroll
  for (int j = 0; j < 8; ++j) { vals[j] = (float)v[j]; s += vals[j]; s2 += vals[j] * vals[j]; }
#pragma unroll
  for (int m_ = 1; m_ < 64; m_ <<= 1) { s += __shfl_xor(s, m_); s2 += __shfl_xor(s2, m_); }
  float mu = s * (1.f / C_);
  float var = s2 * (1.f / C_) - mu * mu;
  float rstd = rsqrtf(var + 1e-5f);
  const float* gp = g + which * C_;
  const float* bp = bta + which * C_;
  f16x8 o;
#pragma unroll
  for (int j = 0; j < 8; ++j) {
    int c = lane * 8 + j;
    o[j] = (f16)((vals[j] - mu) * rstd * gp[c] + bp[c]);
  }
  *(f16x8*)(Y + ((size_t)which * BL_ + token) * C_ + lane * 8) = o;
}

// ---------------------------------------------------------------- q_probe
__global__ __launch_bounds__(256) void qprobe2(const f16* __restrict__ Q,
                                               float* __restrict__ qp) {
  int blk = blockIdx.x;
  int b = blk >> 6;
  int r0 = blk * 64;
  int t = threadIdx.x;
  int c8 = (t & 63) * 8, rg = t >> 6;
  float s[8] = {0.f, 0.f, 0.f, 0.f, 0.f, 0.f, 0.f, 0.f};
#pragma unroll
  for (int i = 0; i < 16; ++i) {
    const f16* row = Q + ((size_t)r0 + rg + i * 4) * C_ + c8;
    f16x8 v = *(const f16x8*)row;
#pragma unroll
    for (int j = 0; j < 8; ++j) s[j] += (float)v[j];
  }
  __shared__ float red[4][520];
#pragma unroll
  for (int j = 0; j < 8; ++j) red[rg][c8 + j] = s[j];
  __syncthreads();
  int c = t * 2;
  float a0 = red[0][c] + red[1][c] + red[2][c] + red[3][c];
  float a1 = red[0][c + 1] + red[1][c + 1] + red[2][c + 1] + red[3][c + 1];
  atomicAdd(&qp[b * C_ + c], a0);
  atomicAdd(&qp[b * C_ + c + 1], a1);
}

// ---------------------------------------------------------------- score logits
__global__ __launch_bounds__(256) void logits_kernel(const f16* __restrict__ Kh,
                                                     const float* __restrict__ qp,
                                                     float* __restrict__ score) {
  int wv = threadIdx.x >> 6, lane = threadIdx.x & 63;
  int token = blockIdx.x * 4 + wv;
  int b = token >> 12;
  int l = token & (L_ - 1);
  const f16* row = Kh + (size_t)token * C_;
  int h = lane >> 3, j0 = (lane & 7) * 8;
  const float* qph = qp + b * C_ + h * DH_ + j0;
  float p = 0.f;
#pragma unroll
  for (int j = 0; j < 8; ++j) p += qph[j] * (float)row[h * DH_ + j0 + j];
  p += __shfl_xor(p, 1); p += __shfl_xor(p, 2); p += __shfl_xor(p, 4);
  if ((lane & 7) == 0)
    score[((size_t)b * H_ + h) * LK_ + 1 + l] = p * (1.f / L_) * 0.125f;
}

// softmax over [1+L] logits (logit[0]=0) + ksum init fused at the end
__global__ __launch_bounds__(256) void softmax_kernel(float* __restrict__ score,
                                                      const float* __restrict__ bkk,
                                                      float* __restrict__ ksum) {
  int bh = blockIdx.x, t = threadIdx.x;
  float* s = score + (size_t)bh * LK_;
  __shared__ float red[256];
  float mx = 0.f;
  for (int i = t; i < L_; i += 256) mx = fmaxf(mx, s[1 + i]);
  red[t] = mx; __syncthreads();
  for (int k = 128; k; k >>= 1) { if (t < k) red[t] = fmaxf(red[t], red[t + k]); __syncthreads(); }
  mx = red[0]; __syncthreads();
  float sum = (t == 0) ? expf(-mx) : 0.f;
  for (int i = t; i < L_; i += 256) { float e = expf(s[1 + i] - mx); s[1 + i] = e; sum += e; }
  red[t] = sum; __syncthreads();
  for (int k = 128; k; k >>= 1) { if (t < k) red[t] += red[t + k]; __syncthreads(); }
  float inv = 1.f / red[0];
  __syncthreads();
  for (int i = t; i < L_; i += 256) s[1 + i] *= inv;
  float s0 = expf(-mx) * inv;
  if (t == 0) s[0] = s0;
  if (t < 64) {
    int h = bh & 7;
    ksum[bh * 64 + t] = s0 * (tanhf(bkk[h * DH_ + t]) + 1.f);
  }
}

// ---------------------------------------------------------------- kv partials
#define PIDX(l, c) ((l) * 68 + (c))
#define AIDX(d, e) ((d) * 68 + (e) + ((((d) >> 3)) << 2))   // bank-skewed
__global__ __launch_bounds__(256, 2) void kv_part_kernel(const f16* __restrict__ phiK,
                                                         const f16* __restrict__ Vh,
                                                         const float* __restrict__ score,
                                                         float* __restrict__ kvp,
                                                         float* __restrict__ ksum) {
  __shared__ float sm0[4416];
  __shared__ float sm1[4416];
  int bh = blockIdx.y, b = bh >> 3, h = bh & 7;
  int part = blockIdx.x;
  int l0 = part * 256;
  int t = threadIdx.x, lane = t & 63, wv = t >> 6;
  int R = (lane >> 3) * 8, Cc = (lane & 7) * 8;
  float acc[8][8] = {};
  float ks[8] = {0.f, 0.f, 0.f, 0.f, 0.f, 0.f, 0.f, 0.f};

  for (int c = 0; c < 4; ++c) {
    int lc = l0 + c * 64;
    __syncthreads();
#pragma unroll
    for (int p = 0; p < 4; ++p) {
      int l = p * 16 + (t >> 4);
      int c4 = (t & 15) * 4;
      size_t grow = ((size_t)b * L_ + lc + l) * C_ + h * DH_ + c4;
      float w = score[(size_t)bh * LK_ + 1 + lc + l];
      f16x4 pk = *(const f16x4*)(phiK + grow);
      f16x4 vvv = *(const f16x4*)(Vh + grow);
      sm0[PIDX(l, c4) + 0] = w * (float)pk[0];
      sm0[PIDX(l, c4) + 1] = w * (float)pk[1];
      sm0[PIDX(l, c4) + 2] = w * (float)pk[2];
      sm0[PIDX(l, c4) + 3] = w * (float)pk[3];
      sm1[PIDX(l, c4) + 0] = (float)vvv[0];
      sm1[PIDX(l, c4) + 1] = (float)vvv[1];
      sm1[PIDX(l, c4) + 2] = (float)vvv[2];
      sm1[PIDX(l, c4) + 3] = (float)vvv[3];
    }
    __syncthreads();
#pragma unroll
    for (int i = 0; i < 16; ++i) {
      int ll = wv * 16 + i;
      float4 a0 = *(const float4*)&sm0[PIDX(ll, R)];
      float4 a1 = *(const float4*)&sm0[PIDX(ll, R + 4)];
      float4 b0 = *(const float4*)&sm1[PIDX(ll, Cc)];
      float4 b1 = *(const float4*)&sm1[PIDX(ll, Cc + 4)];
      float av[8] = {a0.x, a0.y, a0.z, a0.w, a1.x, a1.y, a1.z, a1.w};
      float bv2[8] = {b0.x, b0.y, b0.z, b0.w, b1.x, b1.y, b1.z, b1.w};
#pragma unroll
      for (int ii = 0; ii < 8; ++ii)
#pragma unroll
        for (int jj = 0; jj < 8; ++jj) acc[ii][jj] += av[ii] * bv2[jj];
      if ((lane & 7) == 0) {
#pragma unroll
        for (int ii = 0; ii < 8; ++ii) ks[ii] += av[ii];
      }
    }
  }

  __syncthreads();
  if ((lane & 7) == 0) {
#pragma unroll
    for (int i = 0; i < 8; ++i) sm1[wv * 64 + R + i] = ks[i];
  }
  for (int w = 0; w < 4; ++w) {
    if (wv == w) {
#pragma unroll
      for (int i = 0; i < 8; ++i) {
        float* p0 = &sm0[AIDX(R + i, Cc)];
        if (w == 0) {
          *(float4*)p0 = make_float4(acc[i][0], acc[i][1], acc[i][2], acc[i][3]);
          *(float4*)(p0 + 4) = make_float4(acc[i][4], acc[i][5], acc[i][6], acc[i][7]);
        } else {
          float4 o0 = *(const float4*)p0, o1 = *(const float4*)(p0 + 4);
          o0.x += acc[i][0]; o0.y += acc[i][1]; o0.z += acc[i][2]; o0.w += acc[i][3];
          o1.x += acc[i][4]; o1.y += acc[i][5]; o1.z += acc[i][6]; o1.w += acc[i][7];
          *(float4*)p0 = o0;
          *(float4*)(p0 + 4) = o1;
        }
      }
    }
    __syncthreads();
  }
  if (t < 64) {
    float s = sm1[t] + sm1[64 + t] + sm1[128 + t] + sm1[192 + t];
    atomicAdd(&ksum[bh * 64 + t], s);
  }
  float* dst = kvp + ((size_t)bh * 16 + part) * 4096;
#pragma unroll
  for (int i = 0; i < 16; ++i) {
    int idx = i * 256 + t;
    dst[idx] = sm0[AIDX(idx & 63, idx >> 6)];
  }
}

// merged: block-diag kv build (x<4096) + bottom (x>=4096)
__global__ __launch_bounds__(256) void bd_bottom(const float* __restrict__ kvp,
                                                 f16* __restrict__ BD,
                                                 const f16* __restrict__ phiQ,
                                                 const float* __restrict__ ksum,
                                                 float* __restrict__ bot) {
  if (blockIdx.x < 4096) {
    size_t i = (size_t)blockIdx.x * 256 + threadIdx.x;
    int b = (int)(i >> 18);
    int nk = (int)(i & 262143);
    int n = nk >> 9, k = nk & 511;
    int hn = n >> 6, hk = k >> 6;
    float v = 0.f;
    if (hn == hk) {
      const float* p = kvp + ((size_t)(b * H_ + hn) * 16) * 4096 + (n & 63) * 64 + (k & 63);
#pragma unroll
      for (int pp = 0; pp < 16; ++pp) v += p[pp * 4096];
    }
    BD[i] = (f16)v;
  } else {
    int wv = threadIdx.x >> 6, lane = threadIdx.x & 63;
    int token = (blockIdx.x - 4096) * 4 + wv;
    int b = token >> 12;
    const f16* row = phiQ + (size_t)token * C_;
    int h = lane >> 3, j0 = (lane & 7) * 8;
    const float* ks = ksum + (b * H_ + h) * 64 + j0;
    float p = 0.f;
#pragma unroll
    for (int j = 0; j < 8; ++j) p += ks[j] * (float)row[h * DH_ + j0 + j];
    p += __shfl_xor(p, 1); p += __shfl_xor(p, 2); p += __shfl_xor(p, 4);
    if ((lane & 7) == 0) bot[(size_t)token * H_ + h] = p;
  }
}

// ---------------------------------------------------------------- launch
extern "C" void kernel_launch(void* const* d_in, const int* in_sizes, int n_in,
                              void* d_out, int out_size, void* d_ws, size_t ws_size,
                              hipStream_t stream) {
  (void)in_sizes; (void)n_in; (void)out_size; (void)ws_size;
  const float* x     = (const float*)d_in[0];
  const float* Wq    = (const float*)d_in[1];
  const float* bq    = (const float*)d_in[2];
  const float* gq    = (const float*)d_in[3];
  const float* betaq = (const float*)d_in[4];
  const float* Wk    = (const float*)d_in[5];
  const float* bk    = (const float*)d_in[6];
  const float* gk    = (const float*)d_in[7];
  const float* betak = (const float*)d_in[8];
  const float* Wv    = (const float*)d_in[9];
  const float* bv    = (const float*)d_in[10];
  const float* gv    = (const float*)d_in[11];
  const float* betav = (const float*)d_in[12];
  const float* Wkq   = (const float*)d_in[13];
  const float* bkq   = (const float*)d_in[14];
  const float* Wkk   = (const float*)d_in[15];
  const float* bkk   = (const float*)d_in[16];
  const float* g_at  = (const float*)d_in[17];
  const float* b_at  = (const float*)d_in[18];
  const float* W1    = (const float*)d_in[19];
  const float* b1    = (const float*)d_in[20];
  const float* W2    = (const float*)d_in[21];
  const float* b2    = (const float*)d_in[22];
  float* out = (float*)d_out;

  char* ws = (char*)d_ws;
  size_t off = 0;
  auto alloc = [&](size_t bytes) -> void* {
    void* p = ws + off;
    off += (bytes + 255) & ~(size_t)255;
    return p;
  };
  // U1: tmpqkv(48MB) -> tmpA(16MB) -> h1(64MB), temporally disjoint
  f16* U1    = (f16*)alloc((size_t)BL_ * MLP_ * 2);       // 64 MB
  f16* QKVh  = (f16*)alloc((size_t)3 * BL_ * C_ * 2);     // Qh|Kh|Vh; ah reuses Qh
  f16* phiQK = (f16*)alloc((size_t)2 * BL_ * C_ * 2);     // phiQ|phiK
  f16* xf    = (f16*)alloc((size_t)BL_ * C_ * 2);
  f16* WqkvT = (f16*)alloc((size_t)3 * C_ * C_ * 2);      // Wq|Wk|Wv transposed
  f16* WkqT  = (f16*)alloc((size_t)C_ * C_ * 2);
  f16* WkkT  = (f16*)alloc((size_t)C_ * C_ * 2);
  f16* W1T   = (f16*)alloc((size_t)C_ * MLP_ * 2);
  f16* W2T   = (f16*)alloc((size_t)MLP_ * C_ * 2);
  f16* BD    = (f16*)alloc((size_t)B_ * C_ * C_ * 2);
  float* score = (float*)alloc((size_t)B_ * H_ * LK_ * 4);
  float* qp    = (float*)alloc((size_t)B_ * C_ * 4);
  float* kvp   = (float*)alloc((size_t)B_ * H_ * 16 * 4096 * 4);
  float* ksum  = (float*)alloc((size_t)B_ * H_ * DH_ * 4);
  float* bot   = (float*)alloc((size_t)BL_ * H_ * 4);
  float* bqkv    = (float*)alloc(1536 * 4);
  float* gqkv    = (float*)alloc(1536 * 4);
  float* betaqkv = (float*)alloc(1536 * 4);
  float* bphi    = (float*)alloc(1024 * 4);

  f16* tmpqkv = U1;                  // [16384][1536] f16
  f16* tmpA   = U1;                  // [16384][512] f16
  f16* h1     = U1;                  // [16384][2048] f16
  f16* Qh = QKVh;
  f16* Kh = QKVh + (size_t)BL_ * C_;
  f16* Vh = QKVh + (size_t)2 * BL_ * C_;
  f16* ah = QKVh;                    // reuse Qh region after phi/qprobe done
  f16* phiQ = phiQK;
  f16* phiK = phiQK + (size_t)BL_ * C_;

  dim3 blk(256);

  pack_params<<<6, blk, 0, stream>>>(bq, bk, bv, gq, gk, gv, betaq, betak, betav,
                                     bkq, bkk, bqkv, gqkv, betaqkv, bphi);

  transpose_w5<<<dim3(16, 16, 5), blk, 0, stream>>>(Wq, Wk, Wv, Wkq, Wkk, WqkvT);
  transpose_w<<<dim3(MLP_ / 32, C_ / 32), blk, 0, stream>>>(W1, W1T, C_, MLP_);
  transpose_w<<<dim3(C_ / 32, MLP_ / 32), blk, 0, stream>>>(W2, W2T, MLP_, C_);
  transpose_x<<<dim3(L_ / 32, C_ / 32, B_), blk, 0, stream>>>(x, xf);

  // fused QKV projection: [16384,512] @ [512,1536] -> tmpqkv f16
  gemm64<5><<<dim3(BL_ / 128, 1536 / 128), blk, 0, stream>>>(
      xf, WqkvT, bqkv, tmpqkv, 1536, C_, nullptr, nullptr, nullptr, nullptr, 0, 0, 0, 0, 0);
  // LN all three in one pass -> Qh/Kh/Vh
  ln16<<<3 * BL_ / 4, blk, 0, stream>>>(tmpqkv, gqkv, betaqkv, QKVh, 1);

  hipMemsetAsync(qp, 0, (size_t)B_ * C_ * 4, stream);
  qprobe2<<<BL_ / 64, blk, 0, stream>>>(Qh, qp);

  // phi projections, z-batched (z=0: Qh@Wkq->phiQ, z=1: Kh@Wkk->phiK)
  gemm64<1><<<dim3(BL_ / 128, C_ / 128, 2), blk, 0, stream>>>(
      Qh, WkqT, bphi, phiQ, C_, C_, nullptr, nullptr, nullptr, nullptr,
      (long long)BL_ * C_, (long long)C_ * C_, (long long)BL_ * C_, (long long)C_, 0);

  logits_kernel<<<BL_ / 4, blk, 0, stream>>>(Kh, qp, score);
  softmax_kernel<<<B_ * H_, blk, 0, stream>>>(score, bkk, ksum);

  kv_part_kernel<<<dim3(16, B_ * H_), blk, 0, stream>>>(phiK, Vh, score, kvp, ksum);
  bd_bottom<<<8192, blk, 0, stream>>>(kvp, BD, phiQ, ksum, bot);

  // attention out = (phiQ @ blockdiag(kv)) / (phiQ.ksum + 1e-6), z over batch
  gemm64<3><<<dim3(L_ / 128, C_ / 128, B_), blk, 0, stream>>>(
      phiQ, BD, nullptr, tmpA, C_, C_, bot, nullptr, nullptr, nullptr,
      (long long)L_ * C_, (long long)C_ * C_, (long long)L_ * C_, 0, (long long)L_ * H_);

  ln16<<<BL_ / 4, blk, 0, stream>>>(tmpA, g_at, b_at, ah, 0);

  // MLP up
  gemm64<2><<<dim3(BL_ / 128, MLP_ / 128), blk, 0, stream>>>(
      ah, W1T, b1, h1, MLP_, C_, nullptr, nullptr, nullptr, nullptr, 0, 0, 0, 0, 0);
  // MLP down fused with residual-add + transpose + x-add -> out
  gemm64<6><<<dim3(BL_ / 128, C_ / 128), blk, 0, stream>>>(
      h1, W2T, b2, nullptr, C_, MLP_, nullptr, ah, x, out, 0, 0, 0, 0, 0);
}

// Round 7
// 415.813 us; speedup vs baseline: 1.0324x; 1.0324x over previous
//
#include <hip/hip_runtime.h>
#include <math.h>

#define B_ 4
#define C_ 512
#define L_ 4096
#define H_ 8
#define DH_ 64
#define MLP_ 2048
#define BL_ (B_*L_)      // 16384
#define LK_ (L_+1)       // 4097

typedef _Float16 f16;
typedef _Float16 f16x8 __attribute__((ext_vector_type(8)));
typedef _Float16 f16x4 __attribute__((ext_vector_type(4)));
typedef float f32x4 __attribute__((ext_vector_type(4)));

// async global->LDS, 16B per lane (m97 pattern)
__device__ __forceinline__ void gl16(void* lds, const void* g) {
  __builtin_amdgcn_global_load_lds((const __attribute__((address_space(1))) void*)g,
                                   (__attribute__((address_space(3))) void*)lds,
                                   16, 0, 0);
}

__device__ __forceinline__ float frcp(float x) { return __builtin_amdgcn_rcpf(x); }

// ---------------------------------------------------------------- transposes
__global__ __launch_bounds__(256) void transpose_w5(const float* __restrict__ Wq,
                                                    const float* __restrict__ Wk,
                                                    const float* __restrict__ Wv,
                                                    const float* __restrict__ Wkq,
                                                    const float* __restrict__ Wkk,
                                                    f16* __restrict__ dst) {
  int z = blockIdx.z;
  const float* W = (z == 0) ? Wq : (z == 1) ? Wk : (z == 2) ? Wv : (z == 3) ? Wkq : Wkk;
  f16* Wt = dst + (size_t)z * C_ * C_;
  __shared__ float tile[32][33];
  int n0 = blockIdx.x * 32, k0 = blockIdx.y * 32;
  int tx = threadIdx.x & 31, ty = threadIdx.x >> 5;
#pragma unroll
  for (int i = 0; i < 4; ++i)
    tile[ty + i * 8][tx] = W[(size_t)(k0 + ty + i * 8) * C_ + n0 + tx];
  __syncthreads();
#pragma unroll
  for (int i = 0; i < 4; ++i)
    Wt[(size_t)(n0 + ty + i * 8) * C_ + k0 + tx] = (f16)tile[tx][ty + i * 8];
}

__global__ __launch_bounds__(256) void transpose_w(const float* __restrict__ W,
                                                   f16* __restrict__ Wt, int K, int N) {
  __shared__ float tile[32][33];
  int n0 = blockIdx.x * 32, k0 = blockIdx.y * 32;
  int tx = threadIdx.x & 31, ty = threadIdx.x >> 5;
#pragma unroll
  for (int i = 0; i < 4; ++i)
    tile[ty + i * 8][tx] = W[(size_t)(k0 + ty + i * 8) * N + n0 + tx];
  __syncthreads();
#pragma unroll
  for (int i = 0; i < 4; ++i)
    Wt[(size_t)(n0 + ty + i * 8) * K + k0 + tx] = (f16)tile[tx][ty + i * 8];
}

__global__ __launch_bounds__(256) void transpose_x(const float* __restrict__ x,
                                                   f16* __restrict__ xf) {
  __shared__ float tile[32][33];
  int b = blockIdx.z;
  int l0 = blockIdx.x * 32, c0 = blockIdx.y * 32;
  int tx = threadIdx.x & 31, ty = threadIdx.x >> 5;
#pragma unroll
  for (int i = 0; i < 4; ++i)
    tile[ty + i * 8][tx] = x[((size_t)b * C_ + c0 + ty + i * 8) * L_ + l0 + tx];
  __syncthreads();
#pragma unroll
  for (int i = 0; i < 4; ++i)
    xf[((size_t)b * L_ + l0 + ty + i * 8) * C_ + c0 + tx] = (f16)tile[tx][ty + i * 8];
}

// ------------------------------------------------- pack small param vectors
__global__ __launch_bounds__(256) void pack_params(
    const float* bq, const float* bk, const float* bv,
    const float* gq, const float* gk, const float* gv,
    const float* betaq, const float* betak, const float* betav,
    const float* bkq, const float* bkk,
    float* bqkv, float* gqkv, float* betaqkv, float* bphi) {
  int i = blockIdx.x * 256 + threadIdx.x;  // 0..1535
  int w = i >> 9, c = i & 511;
  bqkv[i]    = (w == 0 ? bq : (w == 1 ? bk : bv))[c];
  gqkv[i]    = (w == 0 ? gq : (w == 1 ? gk : gv))[c];
  betaqkv[i] = (w == 0 ? betaq : (w == 1 ? betak : betav))[c];
  if (i < 1024) bphi[i] = (i < 512) ? bkq[i] : bkk[i - 512];
}

// ---------------------------------------------------------------- GEMM (MFMA)
// C[M,N](f16) = act(A[M,K] @ Bt[N,K]^T + bias) -- 128x128 tiles, BK=32 dbuf
// (32 KB LDS -> ~5 blocks/CU), 16x16x32 MFMA, XOR-swizzled 4-chunk staging
// (R5-proven), LDS-transposed coalesced epilogue.
// EPI: 1 tanh(v)+1   2 gelu (tanh approx)   3 v/(Bot+1e-6)   5 plain bias
//      6 plain bias + a-residual + transposed f32 out (+x)    [MLP-down fusion]
template <int EPI>
__global__ __launch_bounds__(256, 4) void gemm64(const f16* __restrict__ A,
                                                 const f16* __restrict__ Bt,
                                                 const float* __restrict__ bias,
                                                 f16* __restrict__ Ch,
                                                 int N, int K,
                                                 const float* __restrict__ Bot,
                                                 const f16* __restrict__ Ares,
                                                 const float* __restrict__ Xres,
                                                 float* __restrict__ Fout,
                                                 long long zA, long long zB,
                                                 long long zC, long long zBias,
                                                 long long zBot) {
  __shared__ f16 smem[16384];          // 32 KB: 2 x (A 4096 + B 4096); epi [128][128]
  A  += (size_t)blockIdx.z * zA;
  Bt += (size_t)blockIdx.z * zB;
  if (EPI != 6) Ch += (size_t)blockIdx.z * zC;
  if (EPI == 3) Bot += (size_t)blockIdx.z * zBot;
  else          bias += (size_t)blockIdx.z * zBias;

  const int tid = threadIdx.x;
  const int lane = tid & 63, wv = tid >> 6;
  const int wm = wv >> 1, wn = wv & 1;
  const int bm = blockIdx.x * 128, bn = blockIdx.y * 128;
  const int l15 = lane & 15, q = lane >> 4;

  // staging: thread t covers row t>>2 (+p*64), chunk slot t&3; fetched global
  // chunk = slot^(row&3)  ->  frag read slot q^(row&3) yields chunk q
  const int srow = tid >> 2;
  const int schunk = (tid & 3) ^ (srow & 3);
  const f16* pa = A + (size_t)(bm + srow) * K + schunk * 8;
  const f16* pb = Bt + (size_t)(bn + srow) * K + schunk * 8;
  const int sw = (q ^ (l15 & 3)) * 8;  // frag read swizzle (row&3 == l15&3)

  f32x4 acc[4][4] = {};

  // prologue: fill buffer 0  (A rows 0-63, 64-127; B rows 0-63, 64-127)
  gl16(smem + tid * 8, pa);
  gl16(smem + 2048 + tid * 8, pa + (size_t)64 * K);
  gl16(smem + 4096 + tid * 8, pb);
  gl16(smem + 6144 + tid * 8, pb + (size_t)64 * K);

  int cur = 0;
  for (int k0 = 0; k0 < K; k0 += 32) {
    __syncthreads();                   // buf(cur) staged; buf(nxt) readers done
    const int nxt = cur ^ 1;
    if (k0 + 32 < K) {                 // prefetch next k-chunk into other buffer
      f16* nb = smem + nxt * 8192 + tid * 8;
      gl16(nb,        pa + k0 + 32);
      gl16(nb + 2048, pa + (size_t)64 * K + k0 + 32);
      gl16(nb + 4096, pb + k0 + 32);
      gl16(nb + 6144, pb + (size_t)64 * K + k0 + 32);
    }
    const f16* As = smem + cur * 8192;
    const f16* Bs = As + 4096;
    f16x8 af[4], bf[4];
#pragma unroll
    for (int i = 0; i < 4; ++i)
      af[i] = *(const f16x8*)&As[(wm * 64 + i * 16 + l15) * 32 + sw];
#pragma unroll
    for (int j = 0; j < 4; ++j)
      bf[j] = *(const f16x8*)&Bs[(wn * 64 + j * 16 + l15) * 32 + sw];
#pragma unroll
    for (int i = 0; i < 4; ++i)
#pragma unroll
      for (int j = 0; j < 4; ++j)
        acc[i][j] = __builtin_amdgcn_mfma_f32_16x16x32_f16(af[i], bf[j], acc[i][j], 0, 0, 0);
    cur = nxt;
  }

  // ---- epilogue: act -> smem (col-chunk XOR swizzle) -> coalesced out
  __syncthreads();
#pragma unroll
  for (int j = 0; j < 4; ++j) {
    int lc = wn * 64 + j * 16 + l15;
    float bb = (EPI == 3) ? 0.f : bias[bn + lc];
#pragma unroll
    for (int i = 0; i < 4; ++i) {
#pragma unroll
      for (int r = 0; r < 4; ++r) {
        int lr = wm * 64 + i * 16 + q * 4 + r;
        float v = acc[i][j][r] + bb;
        if (EPI == 1) {
          v = 2.0f * frcp(1.0f + __expf(-2.0f * v));      // tanh(v)+1
        } else if (EPI == 2) {
          v = v * frcp(1.0f + __expf(-1.5957691f * (v + 0.044715f * v * v * v)));
        } else if (EPI == 3) {
          v = v * frcp(Bot[(size_t)(bm + lr) * H_ + ((bn + lc) >> 6)] + 1e-6f);
        }
        smem[lr * 128 + ((((lc >> 3) ^ (lr & 15)) << 3) | (lc & 7))] = (f16)v;
      }
    }
  }
  __syncthreads();

  if (EPI != 6) {
#pragma unroll
    for (int p = 0; p < 8; ++p) {
      int idx = p * 256 + tid;
      int row = idx >> 4, ch = idx & 15;
      f16x8 vv = *(const f16x8*)&smem[row * 128 + ((ch ^ (row & 15)) << 3)];
      *(f16x8*)&Ch[(size_t)(bm + row) * N + bn + ch * 8] = vv;
    }
  } else {
    // add a-residual (row-coalesced RMW in LDS)
#pragma unroll
    for (int p = 0; p < 8; ++p) {
      int idx = p * 256 + tid;
      int row = idx >> 4, ch = idx & 15;
      f16x8 av = *(const f16x8*)&Ares[(size_t)(bm + row) * C_ + bn + ch * 8];
      f16* sp = &smem[row * 128 + ((ch ^ (row & 15)) << 3)];
      f16x8 sv = *(const f16x8*)sp;
#pragma unroll
      for (int jj = 0; jj < 8; ++jj) sv[jj] = (f16)((float)sv[jj] + (float)av[jj]);
      *(f16x8*)sp = sv;
    }
    __syncthreads();
    // transposed f32 write: out[b][c][l] = tile[l][c] + x[b][c][l]
    int c = tid & 127, lh = tid >> 7;
    int b = bm >> 12, lbase = (bm & 4095) + lh * 64;
    const float* xp = Xres + ((size_t)b * C_ + bn + c) * L_ + lbase;
    float* op = Fout + ((size_t)b * C_ + bn + c) * L_ + lbase;
    int chi = c >> 3, clo = c & 7;
#pragma unroll
    for (int s = 0; s < 16; ++s) {
      int l = lh * 64 + s * 4;
      float4 xv = *(const float4*)(xp + s * 4);
      float4 r;
      r.x = (float)smem[(l + 0) * 128 + (((chi ^ ((l + 0) & 15)) << 3) | clo)] + xv.x;
      r.y = (float)smem[(l + 1) * 128 + (((chi ^ ((l + 1) & 15)) << 3) | clo)] + xv.y;
      r.z = (float)smem[(l + 2) * 128 + (((chi ^ ((l + 2) & 15)) << 3) | clo)] + xv.z;
      r.w = (float)smem[(l + 3) * 128 + (((chi ^ ((l + 3) & 15)) << 3) | clo)] + xv.w;
      *(float4*)(op + s * 4) = r;
    }
  }
}

// ---------------------------------------------------------------- LayerNorm (f16 in/out)
// threeway=1: X is [49152][512] rows (token*3+which); out which*BL + token.
__global__ __launch_bounds__(256) void ln16(const f16* __restrict__ X,
                                            const float* __restrict__ g,
                                            const float* __restrict__ bta,
                                            f16* __restrict__ Y, int threeway) {
  int wv = threadIdx.x >> 6, lane = threadIdx.x & 63;
  int r = blockIdx.x * 4 + wv;
  int token = r, which = 0;
  if (threeway) { token = r / 3; which = r - token * 3; }
  const f16* xr = X + (size_t)r * C_;
  f16x8 v = *(const f16x8*)(xr + lane * 8);
  float vals[8];
  float s = 0.f, s2 = 0.f;
#pragma unroll
  for (int j = 0; j < 8; ++j) { vals[j] = (float)v[j]; s += vals[j]; s2 += vals[j] * vals[j]; }
#pragma unroll
  for (int m_ = 1; m_ < 64; m_ <<= 1) { s += __shfl_xor(s, m_); s2 += __shfl_xor(s2, m_); }
  float mu = s * (1.f / C_);
  float var = s2 * (1.f / C_) - mu * mu;
  float rstd = rsqrtf(var + 1e-5f);
  const float* gp = g + which * C_;
  const float* bp = bta + which * C_;
  f16x8 o;
#pragma unroll
  for (int j = 0; j < 8; ++j) {
    int c = lane * 8 + j;
    o[j] = (f16)((vals[j] - mu) * rstd * gp[c] + bp[c]);
  }
  *(f16x8*)(Y + ((size_t)which * BL_ + token) * C_ + lane * 8) = o;
}

// ---------------------------------------------------------------- q_probe
__global__ __launch_bounds__(256) void qprobe2(const f16* __restrict__ Q,
                                               float* __restrict__ qp) {
  int blk = blockIdx.x;
  int b = blk >> 6;
  int r0 = blk * 64;
  int t = threadIdx.x;
  int c8 = (t & 63) * 8, rg = t >> 6;
  float s[8] = {0.f, 0.f, 0.f, 0.f, 0.f, 0.f, 0.f, 0.f};
#pragma unroll
  for (int i = 0; i < 16; ++i) {
    const f16* row = Q + ((size_t)r0 + rg + i * 4) * C_ + c8;
    f16x8 v = *(const f16x8*)row;
#pragma unroll
    for (int j = 0; j < 8; ++j) s[j] += (float)v[j];
  }
  __shared__ float red[4][520];
#pragma unroll
  for (int j = 0; j < 8; ++j) red[rg][c8 + j] = s[j];
  __syncthreads();
  int c = t * 2;
  float a0 = red[0][c] + red[1][c] + red[2][c] + red[3][c];
  float a1 = red[0][c + 1] + red[1][c + 1] + red[2][c + 1] + red[3][c + 1];
  atomicAdd(&qp[b * C_ + c], a0);
  atomicAdd(&qp[b * C_ + c + 1], a1);
}

// ---------------------------------------------------------------- score logits
__global__ __launch_bounds__(256) void logits_kernel(const f16* __restrict__ Kh,
                                                     const float* __restrict__ qp,
                                                     float* __restrict__ score) {
  int wv = threadIdx.x >> 6, lane = threadIdx.x & 63;
  int token = blockIdx.x * 4 + wv;
  int b = token >> 12;
  int l = token & (L_ - 1);
  const f16* row = Kh + (size_t)token * C_;
  int h = lane >> 3, j0 = (lane & 7) * 8;
  const float* qph = qp + b * C_ + h * DH_ + j0;
  float p = 0.f;
#pragma unroll
  for (int j = 0; j < 8; ++j) p += qph[j] * (float)row[h * DH_ + j0 + j];
  p += __shfl_xor(p, 1); p += __shfl_xor(p, 2); p += __shfl_xor(p, 4);
  if ((lane & 7) == 0)
    score[((size_t)b * H_ + h) * LK_ + 1 + l] = p * (1.f / L_) * 0.125f;
}

// softmax over [1+L] logits (logit[0]=0) + ksum init fused at the end
__global__ __launch_bounds__(256) void softmax_kernel(float* __restrict__ score,
                                                      const float* __restrict__ bkk,
                                                      float* __restrict__ ksum) {
  int bh = blockIdx.x, t = threadIdx.x;
  float* s = score + (size_t)bh * LK_;
  __shared__ float red[256];
  float mx = 0.f;
  for (int i = t; i < L_; i += 256) mx = fmaxf(mx, s[1 + i]);
  red[t] = mx; __syncthreads();
  for (int k = 128; k; k >>= 1) { if (t < k) red[t] = fmaxf(red[t], red[t + k]); __syncthreads(); }
  mx = red[0]; __syncthreads();
  float sum = (t == 0) ? expf(-mx) : 0.f;
  for (int i = t; i < L_; i += 256) { float e = expf(s[1 + i] - mx); s[1 + i] = e; sum += e; }
  red[t] = sum; __syncthreads();
  for (int k = 128; k; k >>= 1) { if (t < k) red[t] += red[t + k]; __syncthreads(); }
  float inv = 1.f / red[0];
  __syncthreads();
  for (int i = t; i < L_; i += 256) s[1 + i] *= inv;
  float s0 = expf(-mx) * inv;
  if (t == 0) s[0] = s0;
  if (t < 64) {
    int h = bh & 7;
    ksum[bh * 64 + t] = s0 * (tanhf(bkk[h * DH_ + t]) + 1.f);
  }
}

// ---------------------------------------------------------------- kv partials
#define PIDX(l, c) ((l) * 68 + (c))
#define AIDX(d, e) ((d) * 68 + (e) + ((((d) >> 3)) << 2))   // bank-skewed
__global__ __launch_bounds__(256, 2) void kv_part_kernel(const f16* __restrict__ phiK,
                                                         const f16* __restrict__ Vh,
                                                         const float* __restrict__ score,
                                                         float* __restrict__ kvp,
                                                         float* __restrict__ ksum) {
  __shared__ float sm0[4416];
  __shared__ float sm1[4416];
  int bh = blockIdx.y, b = bh >> 3, h = bh & 7;
  int part = blockIdx.x;
  int l0 = part * 256;
  int t = threadIdx.x, lane = t & 63, wv = t >> 6;
  int R = (lane >> 3) * 8, Cc = (lane & 7) * 8;
  float acc[8][8] = {};
  float ks[8] = {0.f, 0.f, 0.f, 0.f, 0.f, 0.f, 0.f, 0.f};

  for (int c = 0; c < 4; ++c) {
    int lc = l0 + c * 64;
    __syncthreads();
#pragma unroll
    for (int p = 0; p < 4; ++p) {
      int l = p * 16 + (t >> 4);
      int c4 = (t & 15) * 4;
      size_t grow = ((size_t)b * L_ + lc + l) * C_ + h * DH_ + c4;
      float w = score[(size_t)bh * LK_ + 1 + lc + l];
      f16x4 pk = *(const f16x4*)(phiK + grow);
      f16x4 vvv = *(const f16x4*)(Vh + grow);
      sm0[PIDX(l, c4) + 0] = w * (float)pk[0];
      sm0[PIDX(l, c4) + 1] = w * (float)pk[1];
      sm0[PIDX(l, c4) + 2] = w * (float)pk[2];
      sm0[PIDX(l, c4) + 3] = w * (float)pk[3];
      sm1[PIDX(l, c4) + 0] = (float)vvv[0];
      sm1[PIDX(l, c4) + 1] = (float)vvv[1];
      sm1[PIDX(l, c4) + 2] = (float)vvv[2];
      sm1[PIDX(l, c4) + 3] = (float)vvv[3];
    }
    __syncthreads();
#pragma unroll
    for (int i = 0; i < 16; ++i) {
      int ll = wv * 16 + i;
      float4 a0 = *(const float4*)&sm0[PIDX(ll, R)];
      float4 a1 = *(const float4*)&sm0[PIDX(ll, R + 4)];
      float4 b0 = *(const float4*)&sm1[PIDX(ll, Cc)];
      float4 b1 = *(const float4*)&sm1[PIDX(ll, Cc + 4)];
      float av[8] = {a0.x, a0.y, a0.z, a0.w, a1.x, a1.y, a1.z, a1.w};
      float bv2[8] = {b0.x, b0.y, b0.z, b0.w, b1.x, b1.y, b1.z, b1.w};
#pragma unroll
      for (int ii = 0; ii < 8; ++ii)
#pragma unroll
        for (int jj = 0; jj < 8; ++jj) acc[ii][jj] += av[ii] * bv2[jj];
      if ((lane & 7) == 0) {
#pragma unroll
        for (int ii = 0; ii < 8; ++ii) ks[ii] += av[ii];
      }
    }
  }

  __syncthreads();
  if ((lane & 7) == 0) {
#pragma unroll
    for (int i = 0; i < 8; ++i) sm1[wv * 64 + R + i] = ks[i];
  }
  for (int w = 0; w < 4; ++w) {
    if (wv == w) {
#pragma unroll
      for (int i = 0; i < 8; ++i) {
        float* p0 = &sm0[AIDX(R + i, Cc)];
        if (w == 0) {
          *(float4*)p0 = make_float4(acc[i][0], acc[i][1], acc[i][2], acc[i][3]);
          *(float4*)(p0 + 4) = make_float4(acc[i][4], acc[i][5], acc[i][6], acc[i][7]);
        } else {
          float4 o0 = *(const float4*)p0, o1 = *(const float4*)(p0 + 4);
          o0.x += acc[i][0]; o0.y += acc[i][1]; o0.z += acc[i][2]; o0.w += acc[i][3];
          o1.x += acc[i][4]; o1.y += acc[i][5]; o1.z += acc[i][6]; o1.w += acc[i][7];
          *(float4*)p0 = o0;
          *(float4*)(p0 + 4) = o1;
        }
      }
    }
    __syncthreads();
  }
  if (t < 64) {
    float s = sm1[t] + sm1[64 + t] + sm1[128 + t] + sm1[192 + t];
    atomicAdd(&ksum[bh * 64 + t], s);
  }
  float* dst = kvp + ((size_t)bh * 16 + part) * 4096;
#pragma unroll
  for (int i = 0; i < 16; ++i) {
    int idx = i * 256 + t;
    dst[idx] = sm0[AIDX(idx & 63, idx >> 6)];
  }
}

// merged: block-diag kv build (x<4096) + bottom (x>=4096)
__global__ __launch_bounds__(256) void bd_bottom(const float* __restrict__ kvp,
                                                 f16* __restrict__ BD,
                                                 const f16* __restrict__ phiQ,
                                                 const float* __restrict__ ksum,
                                                 float* __restrict__ bot) {
  if (blockIdx.x < 4096) {
    size_t i = (size_t)blockIdx.x * 256 + threadIdx.x;
    int b = (int)(i >> 18);
    int nk = (int)(i & 262143);
    int n = nk >> 9, k = nk & 511;
    int hn = n >> 6, hk = k >> 6;
    float v = 0.f;
    if (hn == hk) {
      const float* p = kvp + ((size_t)(b * H_ + hn) * 16) * 4096 + (n & 63) * 64 + (k & 63);
#pragma unroll
      for (int pp = 0; pp < 16; ++pp) v += p[pp * 4096];
    }
    BD[i] = (f16)v;
  } else {
    int wv = threadIdx.x >> 6, lane = threadIdx.x & 63;
    int token = (blockIdx.x - 4096) * 4 + wv;
    int b = token >> 12;
    const f16* row = phiQ + (size_t)token * C_;
    int h = lane >> 3, j0 = (lane & 7) * 8;
    const float* ks = ksum + (b * H_ + h) * 64 + j0;
    float p = 0.f;
#pragma unroll
    for (int j = 0; j < 8; ++j) p += ks[j] * (float)row[h * DH_ + j0 + j];
    p += __shfl_xor(p, 1); p += __shfl_xor(p, 2); p += __shfl_xor(p, 4);
    if ((lane & 7) == 0) bot[(size_t)token * H_ + h] = p;
  }
}

// ---------------------------------------------------------------- launch
extern "C" void kernel_launch(void* const* d_in, const int* in_sizes, int n_in,
                              void* d_out, int out_size, void* d_ws, size_t ws_size,
                              hipStream_t stream) {
  (void)in_sizes; (void)n_in; (void)out_size; (void)ws_size;
  const float* x     = (const float*)d_in[0];
  const float* Wq    = (const float*)d_in[1];
  const float* bq    = (const float*)d_in[2];
  const float* gq    = (const float*)d_in[3];
  const float* betaq = (const float*)d_in[4];
  const float* Wk    = (const float*)d_in[5];
  const float* bk    = (const float*)d_in[6];
  const float* gk    = (const float*)d_in[7];
  const float* betak = (const float*)d_in[8];
  const float* Wv    = (const float*)d_in[9];
  const float* bv    = (const float*)d_in[10];
  const float* gv    = (const float*)d_in[11];
  const float* betav = (const float*)d_in[12];
  const float* Wkq   = (const float*)d_in[13];
  const float* bkq   = (const float*)d_in[14];
  const float* Wkk   = (const float*)d_in[15];
  const float* bkk   = (const float*)d_in[16];
  const float* g_at  = (const float*)d_in[17];
  const float* b_at  = (const float*)d_in[18];
  const float* W1    = (const float*)d_in[19];
  const float* b1    = (const float*)d_in[20];
  const float* W2    = (const float*)d_in[21];
  const float* b2    = (const float*)d_in[22];
  float* out = (float*)d_out;

  char* ws = (char*)d_ws;
  size_t off = 0;
  auto alloc = [&](size_t bytes) -> void* {
    void* p = ws + off;
    off += (bytes + 255) & ~(size_t)255;
    return p;
  };
  // U1: tmpqkv(48MB) -> tmpA(16MB) -> h1(64MB), temporally disjoint
  f16* U1    = (f16*)alloc((size_t)BL_ * MLP_ * 2);       // 64 MB
  f16* QKVh  = (f16*)alloc((size_t)3 * BL_ * C_ * 2);     // Qh|Kh|Vh; ah reuses Qh
  f16* phiQK = (f16*)alloc((size_t)2 * BL_ * C_ * 2);     // phiQ|phiK
  f16* xf    = (f16*)alloc((size_t)BL_ * C_ * 2);
  f16* WqkvT = (f16*)alloc((size_t)3 * C_ * C_ * 2);      // Wq|Wk|Wv transposed
  f16* WkqT  = (f16*)alloc((size_t)C_ * C_ * 2);
  f16* WkkT  = (f16*)alloc((size_t)C_ * C_ * 2);
  f16* W1T   = (f16*)alloc((size_t)C_ * MLP_ * 2);
  f16* W2T   = (f16*)alloc((size_t)MLP_ * C_ * 2);
  f16* BD    = (f16*)alloc((size_t)B_ * C_ * C_ * 2);
  float* score = (float*)alloc((size_t)B_ * H_ * LK_ * 4);
  float* qp    = (float*)alloc((size_t)B_ * C_ * 4);
  float* kvp   = (float*)alloc((size_t)B_ * H_ * 16 * 4096 * 4);
  float* ksum  = (float*)alloc((size_t)B_ * H_ * DH_ * 4);
  float* bot   = (float*)alloc((size_t)BL_ * H_ * 4);
  float* bqkv    = (float*)alloc(1536 * 4);
  float* gqkv    = (float*)alloc(1536 * 4);
  float* betaqkv = (float*)alloc(1536 * 4);
  float* bphi    = (float*)alloc(1024 * 4);

  f16* tmpqkv = U1;                  // [49152][512] f16
  f16* tmpA   = U1;                  // [16384][512] f16
  f16* h1     = U1;                  // [16384][2048] f16
  f16* Qh = QKVh;
  f16* Kh = QKVh + (size_t)BL_ * C_;
  f16* Vh = QKVh + (size_t)2 * BL_ * C_;
  f16* ah = QKVh;                    // reuse Qh region after phi/qprobe done
  f16* phiQ = phiQK;
  f16* phiK = phiQK + (size_t)BL_ * C_;

  dim3 blk(256);

  pack_params<<<6, blk, 0, stream>>>(bq, bk, bv, gq, gk, gv, betaq, betak, betav,
                                     bkq, bkk, bqkv, gqkv, betaqkv, bphi);

  transpose_w5<<<dim3(16, 16, 5), blk, 0, stream>>>(Wq, Wk, Wv, Wkq, Wkk, WqkvT);
  transpose_w<<<dim3(MLP_ / 32, C_ / 32), blk, 0, stream>>>(W1, W1T, C_, MLP_);
  transpose_w<<<dim3(C_ / 32, MLP_ / 32), blk, 0, stream>>>(W2, W2T, MLP_, C_);
  transpose_x<<<dim3(L_ / 32, C_ / 32, B_), blk, 0, stream>>>(x, xf);

  // fused QKV projection: [16384,512] @ [512,1536] -> tmpqkv f16
  gemm64<5><<<dim3(BL_ / 128, 1536 / 128), blk, 0, stream>>>(
      xf, WqkvT, bqkv, tmpqkv, 1536, C_, nullptr, nullptr, nullptr, nullptr, 0, 0, 0, 0, 0);
  // LN all three in one pass -> Qh/Kh/Vh
  ln16<<<3 * BL_ / 4, blk, 0, stream>>>(tmpqkv, gqkv, betaqkv, QKVh, 1);

  hipMemsetAsync(qp, 0, (size_t)B_ * C_ * 4, stream);
  qprobe2<<<BL_ / 64, blk, 0, stream>>>(Qh, qp);

  // phi projections, z-batched (z=0: Qh@Wkq->phiQ, z=1: Kh@Wkk->phiK)
  gemm64<1><<<dim3(BL_ / 128, C_ / 128, 2), blk, 0, stream>>>(
      Qh, WkqT, bphi, phiQ, C_, C_, nullptr, nullptr, nullptr, nullptr,
      (long long)BL_ * C_, (long long)C_ * C_, (long long)BL_ * C_, (long long)C_, 0);

  logits_kernel<<<BL_ / 4, blk, 0, stream>>>(Kh, qp, score);
  softmax_kernel<<<B_ * H_, blk, 0, stream>>>(score, bkk, ksum);

  kv_part_kernel<<<dim3(16, B_ * H_), blk, 0, stream>>>(phiK, Vh, score, kvp, ksum);
  bd_bottom<<<8192, blk, 0, stream>>>(kvp, BD, phiQ, ksum, bot);

  // attention out = (phiQ @ blockdiag(kv)) / (phiQ.ksum + 1e-6), z over batch
  gemm64<3><<<dim3(L_ / 128, C_ / 128, B_), blk, 0, stream>>>(
      phiQ, BD, nullptr, tmpA, C_, C_, bot, nullptr, nullptr, nullptr,
      (long long)L_ * C_, (long long)C_ * C_, (long long)L_ * C_, 0, (long long)L_ * H_);

  ln16<<<BL_ / 4, blk, 0, stream>>>(tmpA, g_at, b_at, ah, 0);

  // MLP up
  gemm64<2><<<dim3(BL_ / 128, MLP_ / 128), blk, 0, stream>>>(
      ah, W1T, b1, h1, MLP_, C_, nullptr, nullptr, nullptr, nullptr, 0, 0, 0, 0, 0);
  // MLP down fused with residual-add + transpose + x-add -> out
  gemm64<6><<<dim3(BL_ / 128, C_ / 128), blk, 0, stream>>>(
      h1, W2T, b2, nullptr, C_, MLP_, nullptr, ah, x, out, 0, 0, 0, 0, 0);
}